// Round 3
// baseline (2499.419 us; speedup 1.0000x reference)
//
#include <hip/hip_runtime.h>

#define NN 100000
#define NE 1600000
#define INDIM 128
#define HID 64
#define NG 1024
#define NB 1563          // ceil(NN/64) buckets of 64 target nodes
#define BN_EPS 1e-5f

typedef unsigned short u16;
typedef unsigned int u32;

__device__ __forceinline__ u16 f2bf(float f) {
    u32 u = __float_as_uint(f);
    u32 r = (u + 0x7fffu + ((u >> 16) & 1u)) >> 16;   // RNE
    return (u16)r;
}
__device__ __forceinline__ float bf2f(u16 b) {
    return __uint_as_float(((u32)b) << 16);
}

// ---------------- graph preprocessing ----------------

__global__ void k_deg(const int* __restrict__ col, int* __restrict__ deg, int E) {
    int e = blockIdx.x * blockDim.x + threadIdx.x;
    if (e < E) atomicAdd(&deg[col[e]], 1);
}

__global__ void k_dinv(const int* __restrict__ deg, float* __restrict__ dinv, int N) {
    int i = blockIdx.x * blockDim.x + threadIdx.x;
    if (i < N) dinv[i] = rsqrtf((float)(deg[i] + 1));  // +1 = self-loop
}

// bucket edge counts = sum of deg over the bucket's 64 nodes.  grid=NB, block=64.
__global__ void k_bcnt(const int* __restrict__ deg, int* __restrict__ bcnt, int N) {
    int b = blockIdx.x, lane = threadIdx.x;
    int node = b * 64 + lane;
    int d = (node < N) ? deg[node] : 0;
    for (int off = 32; off > 0; off >>= 1) d += __shfl_down(d, off, 64);
    if (lane == 0) bcnt[b] = d;
}

// exclusive scan of bcnt[NB] -> bstart.  single block, 256 thr x 7 items.
__global__ void k_bscan(const int* __restrict__ bcnt, int* __restrict__ bstart, int B) {
    __shared__ int ts[256];
    int t = threadIdx.x;
    int loc[7];
    int s = 0;
    for (int i = 0; i < 7; i++) {
        int idx = t * 7 + i;
        loc[i] = (idx < B) ? bcnt[idx] : 0;
        s += loc[i];
    }
    ts[t] = s;
    __syncthreads();
    for (int off = 1; off < 256; off <<= 1) {
        int add = (t >= off) ? ts[t - off] : 0;
        __syncthreads();
        ts[t] += add;
        __syncthreads();
    }
    int ex = ts[t] - s;
    for (int i = 0; i < 7; i++) {
        int idx = t * 7 + i;
        if (idx < B) bstart[idx] = ex;
        ex += loc[i];
    }
}

// partition edges into buckets: appends are sequential per bucket -> L2 combines lines.
__global__ void k_passA(const int* __restrict__ row, const int* __restrict__ col,
                        const int* __restrict__ bstart, int* __restrict__ bcur,
                        uint2* __restrict__ ebuf, int E) {
    int e = blockIdx.x * blockDim.x + threadIdx.x;
    if (e < E) {
        int c = col[e];
        int b = c >> 6;
        int p = bstart[b] + atomicAdd(&bcur[b], 1);
        ebuf[p] = make_uint2((u32)row[e], (u32)c);
    }
}

// ---------------- dense compute ----------------

// m'[node,64] = bf16( (in[node,:]@W) * dinv[node] ).
// If bnStats != nullptr, the staged input is relu(BN(in)) instead of raw in.
template<int K>
__global__ void k_gemm(const float* __restrict__ h, const float* __restrict__ W,
                       const float* __restrict__ dinv, u16* __restrict__ m, int N,
                       const float* __restrict__ bnStats, const float* __restrict__ bnG,
                       const float* __restrict__ bnB) {
    __shared__ float sh[16][K];
    const float invN = 1.0f / (float)N;
    int block0 = blockIdx.x * 16;
    for (int idx = threadIdx.x; idx < 16 * K; idx += 256) {
        int nn = idx / K, kk = idx % K;
        int node = block0 + nn;
        float v = (node < N) ? h[(size_t)node * K + kk] : 0.f;
        if (bnStats) {
            float mean = bnStats[kk] * invN;
            float var = bnStats[K + kk] * invN - mean * mean;
            float sc = bnG[kk] * rsqrtf(var + BN_EPS);
            v = fmaxf((v - mean) * sc + bnB[kk], 0.f);
        }
        sh[nn][kk] = v;
    }
    __syncthreads();
    int colj = threadIdx.x & 63;
    int nl = threadIdx.x >> 6;  // 0..3 (uniform per wave -> LDS broadcast reads)
    float a0 = 0.f, a1 = 0.f, a2 = 0.f, a3 = 0.f;
    #pragma unroll 8
    for (int k = 0; k < K; k++) {
        float w = W[k * HID + colj];  // L1-resident (<=32KB)
        a0 += sh[nl][k] * w;
        a1 += sh[nl + 4][k] * w;
        a2 += sh[nl + 8][k] * w;
        a3 += sh[nl + 12][k] * w;
    }
    int n0 = block0 + nl;
    if (n0 < N)      m[(size_t)n0 * HID + colj]        = f2bf(a0 * dinv[n0]);
    if (n0 + 4 < N)  m[(size_t)(n0 + 4) * HID + colj]  = f2bf(a1 * dinv[n0 + 4]);
    if (n0 + 8 < N)  m[(size_t)(n0 + 8) * HID + colj]  = f2bf(a2 * dinv[n0 + 8]);
    if (n0 + 12 < N) m[(size_t)(n0 + 12) * HID + colj] = f2bf(a3 * dinv[n0 + 12]);
}

// bucketed aggregation: block b owns target nodes [b*64, b*64+64).
// LDS tile[64 nodes][64 feats] init with self-loop message, edges atomicAdd into it,
// epilogue scales by dinv, writes agg, and block-reduces BN stats (sum, sumsq).
__global__ void __launch_bounds__(256)
k_aggb(const u16* __restrict__ m, const float* __restrict__ dinv,
       const uint2* __restrict__ ebuf, const int* __restrict__ bstart,
       const int* __restrict__ bcnt, float* __restrict__ agg,
       float* __restrict__ stats, int N) {
    __shared__ float tile[64][64];
    __shared__ float rs[4][64], rq[4][64];
    int b = blockIdx.x;
    int lane = threadIdx.x & 63, wave = threadIdx.x >> 6;
    int node0 = b * 64;
    #pragma unroll
    for (int i = 0; i < 16; i++) {
        int c = wave * 16 + i;
        int node = node0 + c;
        tile[c][lane] = (node < N) ? bf2f(m[(size_t)node * HID + lane]) : 0.f;
    }
    __syncthreads();
    int s = bstart[b], cnt = bcnt[b];
    for (int base = wave * 64; base < cnt; base += 256) {
        int nb = min(64, cnt - base);
        u32 rr = 0, cc = 0;
        if (lane < nb) {
            uint2 e = ebuf[s + base + lane];
            rr = e.x; cc = e.y;
        }
        #pragma unroll 4
        for (int i = 0; i < nb; i++) {
            int r = __shfl((int)rr, i);
            int c = __shfl((int)cc, i) & 63;
            float v = bf2f(m[(size_t)r * HID + lane]);
            atomicAdd(&tile[c][lane], v);
        }
    }
    __syncthreads();
    float sum = 0.f, sq = 0.f;
    #pragma unroll
    for (int i = 0; i < 16; i++) {
        int c = wave * 16 + i;
        int node = node0 + c;
        if (node < N) {
            float v = tile[c][lane] * dinv[node];
            agg[(size_t)node * HID + lane] = v;
            sum += v; sq += v * v;
        }
    }
    rs[wave][lane] = sum; rq[wave][lane] = sq;
    __syncthreads();
    if (wave == 0) {
        float a = rs[0][lane] + rs[1][lane] + rs[2][lane] + rs[3][lane];
        float q = rq[0][lane] + rq[1][lane] + rq[2][lane] + rq[3][lane];
        atomicAdd(&stats[lane], a);
        atomicAdd(&stats[64 + lane], q);
    }
}

// h2 = relu( BN2(agg2) + relu(BN1(agg1)) )
__global__ void k_bn2(const float* __restrict__ agg1, const float* __restrict__ agg2,
                      const float* __restrict__ st1, const float* __restrict__ st2,
                      const float* __restrict__ g1, const float* __restrict__ be1,
                      const float* __restrict__ g2, const float* __restrict__ be2,
                      float* __restrict__ out, int N) {
    const float invN = 1.0f / (float)N;
    size_t total = (size_t)N * HID;
    for (size_t idx = blockIdx.x * (size_t)blockDim.x + threadIdx.x; idx < total;
         idx += (size_t)gridDim.x * blockDim.x) {
        int f = (int)(idx & 63);
        float m1 = st1[f] * invN;
        float v1 = st1[64 + f] * invN - m1 * m1;
        float s1 = g1[f] * rsqrtf(v1 + BN_EPS);
        float h1 = fmaxf((agg1[idx] - m1) * s1 + be1[f], 0.f);
        float m2 = st2[f] * invN;
        float v2 = st2[64 + f] * invN - m2 * m2;
        float s2 = g2[f] * rsqrtf(v2 + BN_EPS);
        float h2 = (agg2[idx] - m2) * s2 + be2[f] + h1;
        out[idx] = fmaxf(h2, 0.f);
    }
}

// sorted-batch run-length pooling with BN3+relu applied inline.
__global__ void k_pool(const float* __restrict__ agg3, const float* __restrict__ st3,
                       const float* __restrict__ g3, const float* __restrict__ be3,
                       const int* __restrict__ batch, float* __restrict__ pooled,
                       float* __restrict__ gcnt, int N) {
    int lane = threadIdx.x;  // blockDim = 64
    int start = blockIdx.x * 64;
    if (start >= N) return;
    const float invN = 1.0f / (float)N;
    float mean = st3[lane] * invN;
    float var = st3[64 + lane] * invN - mean * mean;
    float sc = g3[lane] * rsqrtf(var + BN_EPS);
    float bb = be3[lane];
    int end = min(start + 64, N);
    int gcur = batch[start];
    float acc = 0.f; int run = 0;
    for (int n = start; n < end; n++) {
        int g = batch[n];
        if (g != gcur) {
            atomicAdd(&pooled[gcur * HID + lane], acc);
            if (lane == 0) atomicAdd(&gcnt[gcur], (float)run);
            acc = 0.f; run = 0; gcur = g;
        }
        acc += fmaxf((agg3[(size_t)n * HID + lane] - mean) * sc + bb, 0.f);
        run++;
    }
    atomicAdd(&pooled[gcur * HID + lane], acc);
    if (lane == 0) atomicAdd(&gcnt[gcur], (float)run);
}

// out[g] = dot(pooled[g]/max(cnt,1), fcw) + fcb.  wave per graph.
__global__ void k_final(const float* __restrict__ pooled, const float* __restrict__ gcnt,
                        const float* __restrict__ fcw, const float* __restrict__ fcb,
                        float* __restrict__ out) {
    int g = (int)((blockIdx.x * (size_t)blockDim.x + threadIdx.x) >> 6);
    int lane = threadIdx.x & 63;
    if (g >= NG) return;
    float c = fmaxf(gcnt[g], 1.f);
    float v = pooled[g * HID + lane] / c * fcw[lane];
    for (int off = 32; off > 0; off >>= 1) v += __shfl_down(v, off, 64);
    if (lane == 0) out[g] = v + fcb[0];
}

// ---------------- launch ----------------

extern "C" void kernel_launch(void* const* d_in, const int* in_sizes, int n_in,
                              void* d_out, int out_size, void* d_ws, size_t ws_size,
                              hipStream_t stream) {
    const float* x    = (const float*)d_in[0];
    const int*   ei   = (const int*)d_in[1];
    const int*   batch= (const int*)d_in[2];
    const float* w1   = (const float*)d_in[3];
    const float* g1   = (const float*)d_in[5];
    const float* be1  = (const float*)d_in[6];
    const float* w2   = (const float*)d_in[7];
    const float* g2   = (const float*)d_in[9];
    const float* be2  = (const float*)d_in[10];
    const float* w3   = (const float*)d_in[11];
    const float* g3   = (const float*)d_in[13];
    const float* be3  = (const float*)d_in[14];
    const float* fcw  = (const float*)d_in[15];
    const float* fcb  = (const float*)d_in[16];
    float* out = (float*)d_out;

    const int N = NN, E = NE;
    const int* erow = ei;       // edge_index[0] = source
    const int* ecol = ei + E;   // edge_index[1] = target

    char* ws = (char*)d_ws;
    size_t off = 0;
    auto alloc = [&](size_t bytes) -> char* {
        char* p = ws + off;
        off = (off + bytes + 255) & ~(size_t)255;
        return p;
    };
    int*   deg    = (int*)alloc((size_t)N * 4);
    float* dinv   = (float*)alloc((size_t)N * 4);
    int*   bcnt   = (int*)alloc((size_t)NB * 4);
    int*   bstart = (int*)alloc((size_t)NB * 4);
    int*   bcur   = (int*)alloc((size_t)NB * 4);
    uint2* ebuf   = (uint2*)alloc((size_t)E * 8);        // bucketed (row,col)
    u16*   bufM   = (u16*)alloc((size_t)N * HID * 2);    // m' (bf16, dinv-scaled)
    float* aggB1  = (float*)alloc((size_t)N * HID * 4);  // agg1, later reused as agg3
    float* aggB2  = (float*)alloc((size_t)N * HID * 4);  // agg2
    float* bufH2  = (float*)alloc((size_t)N * HID * 4);  // h2
    float* stats  = (float*)alloc(3 * 128 * 4);
    float* pooled = (float*)alloc((size_t)NG * HID * 4);
    float* gcnt   = (float*)alloc((size_t)NG * 4);
    (void)ws_size; (void)in_sizes; (void)n_in; (void)out_size;

    float* aggB3 = aggB1;  // reuse: aggB1 last read in k_bn2, before layer-3 agg

    hipMemsetAsync(deg, 0, (size_t)N * 4, stream);
    hipMemsetAsync(bcur, 0, (size_t)NB * 4, stream);
    hipMemsetAsync(stats, 0, 3 * 128 * 4, stream);
    hipMemsetAsync(pooled, 0, (size_t)NG * HID * 4, stream);
    hipMemsetAsync(gcnt, 0, (size_t)NG * 4, stream);

    const int nbN = (N + 255) / 256;       // 391
    const int nbE = (E + 255) / 256;       // 6250
    const int nbNode16 = (N + 15) / 16;    // 6250
    const int nbElem = (int)(((size_t)N * HID + 255) / 256);  // 25000

    k_deg<<<nbE, 256, 0, stream>>>(ecol, deg, E);
    k_dinv<<<nbN, 256, 0, stream>>>(deg, dinv, N);
    k_bcnt<<<NB, 64, 0, stream>>>(deg, bcnt, N);
    k_bscan<<<1, 256, 0, stream>>>(bcnt, bstart, NB);
    k_passA<<<nbE, 256, 0, stream>>>(erow, ecol, bstart, bcur, ebuf, E);

    // layer 1
    k_gemm<INDIM><<<nbNode16, 256, 0, stream>>>(x, w1, dinv, bufM, N,
                                                nullptr, nullptr, nullptr);
    k_aggb<<<NB, 256, 0, stream>>>(bufM, dinv, ebuf, bstart, bcnt, aggB1, stats, N);

    // layer 2 (gemm stages relu(BN1(agg1)))
    k_gemm<HID><<<nbNode16, 256, 0, stream>>>(aggB1, w2, dinv, bufM, N,
                                              stats, g1, be1);
    k_aggb<<<NB, 256, 0, stream>>>(bufM, dinv, ebuf, bstart, bcnt, aggB2, stats + 128, N);

    // h2 = relu(BN2(agg2) + relu(BN1(agg1)))
    k_bn2<<<nbElem, 256, 0, stream>>>(aggB1, aggB2, stats, stats + 128,
                                      g1, be1, g2, be2, bufH2, N);

    // layer 3
    k_gemm<HID><<<nbNode16, 256, 0, stream>>>(bufH2, w3, dinv, bufM, N,
                                              nullptr, nullptr, nullptr);
    k_aggb<<<NB, 256, 0, stream>>>(bufM, dinv, ebuf, bstart, bcnt, aggB3, stats + 256, N);

    // pool (BN3+relu inline) + final
    k_pool<<<(N + 63) / 64, 64, 0, stream>>>(aggB3, stats + 256, g3, be3,
                                             batch, pooled, gcnt, N);
    k_final<<<(NG * 64) / 256, 256, 0, stream>>>(pooled, gcnt, fcw, fcb, out);
}

// Round 4
// 839.814 us; speedup vs baseline: 2.9762x; 2.9762x over previous
//
#include <hip/hip_runtime.h>

#define NN 100000
#define NE 1600000
#define INDIM 128
#define HID 64
#define NG 1024
#define NB 1563          // ceil(NN/64) buckets of 64 target nodes
#define BN_EPS 1e-5f

typedef unsigned short u16;
typedef unsigned int u32;

__device__ __forceinline__ u16 f2bf(float f) {
    u32 u = __float_as_uint(f);
    u32 r = (u + 0x7fffu + ((u >> 16) & 1u)) >> 16;   // RNE
    return (u16)r;
}
__device__ __forceinline__ float bf2f(u16 b) {
    return __uint_as_float(((u32)b) << 16);
}

// ---------------- graph preprocessing ----------------

__global__ void k_deg(const int* __restrict__ col, int* __restrict__ deg, int E) {
    int e = blockIdx.x * blockDim.x + threadIdx.x;
    if (e < E) atomicAdd(&deg[col[e]], 1);
}

__global__ void k_dinv(const int* __restrict__ deg, float* __restrict__ dinv, int N) {
    int i = blockIdx.x * blockDim.x + threadIdx.x;
    if (i < N) dinv[i] = rsqrtf((float)(deg[i] + 1));  // +1 = self-loop
}

__global__ void k_scan1(const int* __restrict__ deg, int* __restrict__ bsums, int N) {
    __shared__ int s[256];
    int i = blockIdx.x * 256 + threadIdx.x;
    s[threadIdx.x] = (i < N) ? deg[i] : 0;
    __syncthreads();
    for (int off = 128; off > 0; off >>= 1) {
        if (threadIdx.x < off) s[threadIdx.x] += s[threadIdx.x + off];
        __syncthreads();
    }
    if (threadIdx.x == 0) bsums[blockIdx.x] = s[0];
}

__global__ void k_scan2(int* __restrict__ bsums, int nb, int* __restrict__ offs, int N, int E) {
    __shared__ int s[512];
    int t = threadIdx.x;
    int v = (t < nb) ? bsums[t] : 0;
    s[t] = v;
    __syncthreads();
    for (int off = 1; off < 512; off <<= 1) {
        int add = (t >= off) ? s[t - off] : 0;
        __syncthreads();
        s[t] += add;
        __syncthreads();
    }
    if (t < nb) bsums[t] = s[t] - v;  // exclusive block bases
    if (t == 0) offs[N] = E;
}

__global__ void k_scan3(const int* __restrict__ deg, const int* __restrict__ bsums,
                        int* __restrict__ offs, int N) {
    __shared__ int s[256];
    int i = blockIdx.x * 256 + threadIdx.x;
    int v = (i < N) ? deg[i] : 0;
    s[threadIdx.x] = v;
    __syncthreads();
    for (int off = 1; off < 256; off <<= 1) {
        int add = (threadIdx.x >= off) ? s[threadIdx.x - off] : 0;
        __syncthreads();
        s[threadIdx.x] += add;
        __syncthreads();
    }
    if (i < N) offs[i] = bsums[blockIdx.x] + s[threadIdx.x] - v;
}

// bucketize edges by target bucket (col>>6); packed entry = (row<<6)|(col&63).
// appends are sequential per bucket cursor -> L2 write-combines lines.
__global__ void k_passA(const int* __restrict__ row, const int* __restrict__ col,
                        const int* __restrict__ offs, int* __restrict__ bcur,
                        u32* __restrict__ ebuf, int E) {
    int e = blockIdx.x * blockDim.x + threadIdx.x;
    if (e < E) {
        int c = col[e];
        int b = c >> 6;
        int p = offs[b << 6] + atomicAdd(&bcur[b], 1);  // offs[64b] = bucket start
        ebuf[p] = ((u32)row[e] << 6) | (u32)(c & 63);
    }
}

// build per-node CSR rows[] from bucketized ebuf: one block per bucket, LDS cursors.
// writes land in the bucket's contiguous ~deg*4B span -> fully combined lines.
__global__ void k_fill2(const u32* __restrict__ ebuf, const int* __restrict__ offs,
                        int* __restrict__ rows, int N) {
    __shared__ int cur[64];
    int b = blockIdx.x, t = threadIdx.x;
    if (t < 64) cur[t] = 0;
    __syncthreads();
    int s = offs[b << 6];
    int e = offs[min((b << 6) + 64, N)];
    for (int i = s + t; i < e; i += 256) {
        u32 v = ebuf[i];
        int c = (int)(v & 63u);
        int node = (b << 6) + c;
        int p = offs[node] + atomicAdd(&cur[c], 1);
        rows[p] = (int)(v >> 6);
    }
}

// ---------------- dense compute ----------------

// m'[node,64] = bf16( (in[node,:]@W) * dinv[node] ).
// If bnStats != nullptr, the staged input is relu(BN(in)) instead of raw in.
template<int K>
__global__ void k_gemm(const float* __restrict__ h, const float* __restrict__ W,
                       const float* __restrict__ dinv, u16* __restrict__ m, int N,
                       const float* __restrict__ bnStats, const float* __restrict__ bnG,
                       const float* __restrict__ bnB) {
    __shared__ float sh[16][K];
    const float invN = 1.0f / (float)N;
    int block0 = blockIdx.x * 16;
    for (int idx = threadIdx.x; idx < 16 * K; idx += 256) {
        int nn = idx / K, kk = idx % K;
        int node = block0 + nn;
        float v = (node < N) ? h[(size_t)node * K + kk] : 0.f;
        if (bnStats) {
            float mean = bnStats[kk] * invN;
            float var = bnStats[K + kk] * invN - mean * mean;
            float sc = bnG[kk] * rsqrtf(var + BN_EPS);
            v = fmaxf((v - mean) * sc + bnB[kk], 0.f);
        }
        sh[nn][kk] = v;
    }
    __syncthreads();
    int colj = threadIdx.x & 63;
    int nl = threadIdx.x >> 6;  // 0..3 (uniform per wave -> LDS broadcast reads)
    float a0 = 0.f, a1 = 0.f, a2 = 0.f, a3 = 0.f;
    #pragma unroll 8
    for (int k = 0; k < K; k++) {
        float w = W[k * HID + colj];  // L1-resident (<=32KB)
        a0 += sh[nl][k] * w;
        a1 += sh[nl + 4][k] * w;
        a2 += sh[nl + 8][k] * w;
        a3 += sh[nl + 12][k] * w;
    }
    int n0 = block0 + nl;
    if (n0 < N)      m[(size_t)n0 * HID + colj]        = f2bf(a0 * dinv[n0]);
    if (n0 + 4 < N)  m[(size_t)(n0 + 4) * HID + colj]  = f2bf(a1 * dinv[n0 + 4]);
    if (n0 + 8 < N)  m[(size_t)(n0 + 8) * HID + colj]  = f2bf(a2 * dinv[n0 + 8]);
    if (n0 + 12 < N) m[(size_t)(n0 + 12) * HID + colj] = f2bf(a3 * dinv[n0 + 12]);
}

// agg[i,:] = dinv[i] * ( m'[i,:] + sum_{e: col=i} m'[row_e,:] )
// one wave per node, lane = feature.  bf16 gathers = 128B/row = 1 line.
__global__ void k_agg(const u16* __restrict__ m, const float* __restrict__ dinv,
                      const int* __restrict__ offs, const int* __restrict__ rows,
                      float* __restrict__ agg, int N) {
    int node = (int)((blockIdx.x * (size_t)blockDim.x + threadIdx.x) >> 6);
    int lane = threadIdx.x & 63;
    if (node >= N) return;
    float di = dinv[node];
    float acc = bf2f(m[(size_t)node * HID + lane]);
    int s = offs[node], e = offs[node + 1];
    #pragma unroll 4
    for (int j = s; j < e; j++) {
        int r = rows[j];
        acc += bf2f(m[(size_t)r * HID + lane]);
    }
    agg[(size_t)node * HID + lane] = acc * di;
}

// per-feature sum and sumsq -> stats[0:64]=sum, stats[64:128]=sumsq
__global__ void k_stats(const float* __restrict__ agg, float* __restrict__ stats, int N) {
    int f = threadIdx.x & 63;
    int part = threadIdx.x >> 6;  // 0..3
    float s = 0.f, sq = 0.f;
    for (int node = blockIdx.x * 4 + part; node < N; node += gridDim.x * 4) {
        float v = agg[(size_t)node * HID + f];
        s += v; sq += v * v;
    }
    __shared__ float ss[4][64], sg[4][64];
    ss[part][f] = s; sg[part][f] = sq;
    __syncthreads();
    if (part == 0) {
        s  = ss[0][f] + ss[1][f] + ss[2][f] + ss[3][f];
        sq = sg[0][f] + sg[1][f] + sg[2][f] + sg[3][f];
        atomicAdd(&stats[f], s);
        atomicAdd(&stats[64 + f], sq);
    }
}

// h2 = relu( BN2(agg2) + relu(BN1(agg1)) )
__global__ void k_bn2(const float* __restrict__ agg1, const float* __restrict__ agg2,
                      const float* __restrict__ st1, const float* __restrict__ st2,
                      const float* __restrict__ g1, const float* __restrict__ be1,
                      const float* __restrict__ g2, const float* __restrict__ be2,
                      float* __restrict__ out, int N) {
    const float invN = 1.0f / (float)N;
    size_t total = (size_t)N * HID;
    for (size_t idx = blockIdx.x * (size_t)blockDim.x + threadIdx.x; idx < total;
         idx += (size_t)gridDim.x * blockDim.x) {
        int f = (int)(idx & 63);
        float m1 = st1[f] * invN;
        float v1 = st1[64 + f] * invN - m1 * m1;
        float s1 = g1[f] * rsqrtf(v1 + BN_EPS);
        float h1 = fmaxf((agg1[idx] - m1) * s1 + be1[f], 0.f);
        float m2 = st2[f] * invN;
        float v2 = st2[64 + f] * invN - m2 * m2;
        float s2 = g2[f] * rsqrtf(v2 + BN_EPS);
        float h2 = (agg2[idx] - m2) * s2 + be2[f] + h1;
        out[idx] = fmaxf(h2, 0.f);
    }
}

// sorted-batch run-length pooling with BN3+relu applied inline.
__global__ void k_pool(const float* __restrict__ agg3, const float* __restrict__ st3,
                       const float* __restrict__ g3, const float* __restrict__ be3,
                       const int* __restrict__ batch, float* __restrict__ pooled,
                       float* __restrict__ gcnt, int N) {
    int lane = threadIdx.x;  // blockDim = 64
    int start = blockIdx.x * 64;
    if (start >= N) return;
    const float invN = 1.0f / (float)N;
    float mean = st3[lane] * invN;
    float var = st3[64 + lane] * invN - mean * mean;
    float sc = g3[lane] * rsqrtf(var + BN_EPS);
    float bb = be3[lane];
    int end = min(start + 64, N);
    int gcur = batch[start];
    float acc = 0.f; int run = 0;
    for (int n = start; n < end; n++) {
        int g = batch[n];
        if (g != gcur) {
            atomicAdd(&pooled[gcur * HID + lane], acc);
            if (lane == 0) atomicAdd(&gcnt[gcur], (float)run);
            acc = 0.f; run = 0; gcur = g;
        }
        acc += fmaxf((agg3[(size_t)n * HID + lane] - mean) * sc + bb, 0.f);
        run++;
    }
    atomicAdd(&pooled[gcur * HID + lane], acc);
    if (lane == 0) atomicAdd(&gcnt[gcur], (float)run);
}

// out[g] = dot(pooled[g]/max(cnt,1), fcw) + fcb.  wave per graph.
__global__ void k_final(const float* __restrict__ pooled, const float* __restrict__ gcnt,
                        const float* __restrict__ fcw, const float* __restrict__ fcb,
                        float* __restrict__ out) {
    int g = (int)((blockIdx.x * (size_t)blockDim.x + threadIdx.x) >> 6);
    int lane = threadIdx.x & 63;
    if (g >= NG) return;
    float c = fmaxf(gcnt[g], 1.f);
    float v = pooled[g * HID + lane] / c * fcw[lane];
    for (int off = 32; off > 0; off >>= 1) v += __shfl_down(v, off, 64);
    if (lane == 0) out[g] = v + fcb[0];
}

// ---------------- launch ----------------

extern "C" void kernel_launch(void* const* d_in, const int* in_sizes, int n_in,
                              void* d_out, int out_size, void* d_ws, size_t ws_size,
                              hipStream_t stream) {
    const float* x    = (const float*)d_in[0];
    const int*   ei   = (const int*)d_in[1];
    const int*   batch= (const int*)d_in[2];
    const float* w1   = (const float*)d_in[3];
    const float* g1   = (const float*)d_in[5];
    const float* be1  = (const float*)d_in[6];
    const float* w2   = (const float*)d_in[7];
    const float* g2   = (const float*)d_in[9];
    const float* be2  = (const float*)d_in[10];
    const float* w3   = (const float*)d_in[11];
    const float* g3   = (const float*)d_in[13];
    const float* be3  = (const float*)d_in[14];
    const float* fcw  = (const float*)d_in[15];
    const float* fcb  = (const float*)d_in[16];
    float* out = (float*)d_out;

    const int N = NN, E = NE;
    const int* erow = ei;       // edge_index[0] = source
    const int* ecol = ei + E;   // edge_index[1] = target

    char* ws = (char*)d_ws;
    size_t off = 0;
    auto alloc = [&](size_t bytes) -> char* {
        char* p = ws + off;
        off = (off + bytes + 255) & ~(size_t)255;
        return p;
    };
    int*   deg    = (int*)alloc((size_t)N * 4);
    float* dinv   = (float*)alloc((size_t)N * 4);
    int*   offs   = (int*)alloc((size_t)(N + 1) * 4);
    int*   bcur   = (int*)alloc((size_t)NB * 4);
    int*   bsums  = (int*)alloc(512 * 4);
    u32*   ebuf   = (u32*)alloc((size_t)E * 4);          // bucketized packed edges
    int*   rows   = (int*)alloc((size_t)E * 4);          // per-node CSR sources
    u16*   bufM   = (u16*)alloc((size_t)N * HID * 2);    // m' (bf16, dinv-scaled)
    float* aggB1  = (float*)alloc((size_t)N * HID * 4);  // agg1, later reused as agg3
    float* aggB2  = (float*)alloc((size_t)N * HID * 4);  // agg2
    float* bufH2  = (float*)alloc((size_t)N * HID * 4);  // h2
    float* stats  = (float*)alloc(3 * 128 * 4);
    float* pooled = (float*)alloc((size_t)NG * HID * 4);
    float* gcnt   = (float*)alloc((size_t)NG * 4);
    (void)ws_size; (void)in_sizes; (void)n_in; (void)out_size;

    float* aggB3 = aggB1;  // reuse: aggB1 last read in k_bn2, before layer-3 agg

    hipMemsetAsync(deg, 0, (size_t)N * 4, stream);
    hipMemsetAsync(bcur, 0, (size_t)NB * 4, stream);
    hipMemsetAsync(stats, 0, 3 * 128 * 4, stream);
    hipMemsetAsync(pooled, 0, (size_t)NG * HID * 4, stream);
    hipMemsetAsync(gcnt, 0, (size_t)NG * 4, stream);

    const int nbN = (N + 255) / 256;       // 391
    const int nbE = (E + 255) / 256;       // 6250
    const int nbNode16 = (N + 15) / 16;    // 6250
    const int nbElem = (int)(((size_t)N * HID + 255) / 256);  // 25000

    k_deg<<<nbE, 256, 0, stream>>>(ecol, deg, E);
    k_dinv<<<nbN, 256, 0, stream>>>(deg, dinv, N);
    k_scan1<<<nbN, 256, 0, stream>>>(deg, bsums, N);
    k_scan2<<<1, 512, 0, stream>>>(bsums, nbN, offs, N, E);
    k_scan3<<<nbN, 256, 0, stream>>>(deg, bsums, offs, N);
    k_passA<<<nbE, 256, 0, stream>>>(erow, ecol, offs, bcur, ebuf, E);
    k_fill2<<<NB, 256, 0, stream>>>(ebuf, offs, rows, N);

    // layer 1
    k_gemm<INDIM><<<nbNode16, 256, 0, stream>>>(x, w1, dinv, bufM, N,
                                                nullptr, nullptr, nullptr);
    k_agg<<<nbElem, 256, 0, stream>>>(bufM, dinv, offs, rows, aggB1, N);
    k_stats<<<400, 256, 0, stream>>>(aggB1, stats, N);

    // layer 2 (gemm stages relu(BN1(agg1)))
    k_gemm<HID><<<nbNode16, 256, 0, stream>>>(aggB1, w2, dinv, bufM, N,
                                              stats, g1, be1);
    k_agg<<<nbElem, 256, 0, stream>>>(bufM, dinv, offs, rows, aggB2, N);
    k_stats<<<400, 256, 0, stream>>>(aggB2, stats + 128, N);

    // h2 = relu(BN2(agg2) + relu(BN1(agg1)))
    k_bn2<<<nbElem, 256, 0, stream>>>(aggB1, aggB2, stats, stats + 128,
                                      g1, be1, g2, be2, bufH2, N);

    // layer 3
    k_gemm<HID><<<nbNode16, 256, 0, stream>>>(bufH2, w3, dinv, bufM, N,
                                              nullptr, nullptr, nullptr);
    k_agg<<<nbElem, 256, 0, stream>>>(bufM, dinv, offs, rows, aggB3, N);
    k_stats<<<400, 256, 0, stream>>>(aggB3, stats + 256, N);

    // pool (BN3+relu inline) + final
    k_pool<<<(N + 63) / 64, 64, 0, stream>>>(aggB3, stats + 256, g3, be3,
                                             batch, pooled, gcnt, N);
    k_final<<<(NG * 64) / 256, 256, 0, stream>>>(pooled, gcnt, fcw, fcb, out);
}

// Round 6
// 638.151 us; speedup vs baseline: 3.9167x; 1.3160x over previous
//
#include <hip/hip_runtime.h>

#define NN 100000
#define NE 1600000
#define INDIM 128
#define HID 64
#define NG 1024
#define NB 1563            // ceil(NN/64) buckets of 64 target nodes
#define SCB 64             // scatter blocks (private-region multisplit)
#define EPB ((NE + SCB - 1) / SCB)   // 25000 edges per scatter block
#define SEGCAP 2048        // max edges per bucket (avg 1024, Poisson; 32-sigma margin)
#define BN_EPS 1e-5f

typedef unsigned short u16;
typedef unsigned int u32;

__device__ __forceinline__ u16 f2bf(float f) {
    u32 u = __float_as_uint(f);
    u32 r = (u + 0x7fffu + ((u >> 16) & 1u)) >> 16;   // RNE
    return (u16)r;
}
__device__ __forceinline__ float bf2f(u16 b) {
    return __uint_as_float(((u32)b) << 16);
}

// ---------------- graph preprocessing ----------------

// per-block bucket histogram (LDS) + global per-node degree (fused old k_deg).
__global__ void k_hist(const int* __restrict__ col, int* __restrict__ hist,
                       int* __restrict__ deg, int E) {
    __shared__ int h[NB];
    int b = blockIdx.x;
    for (int i = threadIdx.x; i < NB; i += 256) h[i] = 0;
    __syncthreads();
    int s = b * EPB, e = min(s + EPB, E);
    for (int i = s + threadIdx.x; i < e; i += 256) {
        int c = col[i];
        atomicAdd(&h[c >> 6], 1);
        atomicAdd(&deg[c], 1);
    }
    __syncthreads();
    for (int i = threadIdx.x; i < NB; i += 256) hist[b * NB + i] = h[i];
}

__global__ void k_dinv(const int* __restrict__ deg, float* __restrict__ dinv, int N) {
    int i = blockIdx.x * blockDim.x + threadIdx.x;
    if (i < N) dinv[i] = rsqrtf((float)(deg[i] + 1));  // +1 = self-loop
}

// bucket totals: bcnt[bucket] = sum over scatter blocks (coalesced per iteration).
__global__ void k_btot(const int* __restrict__ hist, int* __restrict__ bcnt) {
    int t = blockIdx.x * 256 + threadIdx.x;
    if (t < NB) {
        int s = 0;
        for (int b = 0; b < SCB; b++) s += hist[b * NB + t];
        bcnt[t] = s;
    }
}

// exclusive scan of bcnt[NB] -> bstart (single block, 256 thr x 7 items).
__global__ void k_bscan(const int* __restrict__ bcnt, int* __restrict__ bstart, int B, int E) {
    __shared__ int ts[256];
    int t = threadIdx.x;
    int loc[7];
    int s = 0;
    for (int i = 0; i < 7; i++) {
        int idx = t * 7 + i;
        loc[i] = (idx < B) ? bcnt[idx] : 0;
        s += loc[i];
    }
    ts[t] = s;
    __syncthreads();
    for (int off = 1; off < 256; off <<= 1) {
        int add = (t >= off) ? ts[t - off] : 0;
        __syncthreads();
        ts[t] += add;
        __syncthreads();
    }
    int ex = ts[t] - s;
    for (int i = 0; i < 7; i++) {
        int idx = t * 7 + i;
        if (idx < B) bstart[idx] = ex;
        ex += loc[i];
    }
    if (t == 0) bstart[B] = E;
}

// convert hist[block][bucket] into absolute write bases:
// base = bstart[bucket] + prefix over earlier blocks.  coalesced per iteration.
__global__ void k_hcol(int* __restrict__ hist, const int* __restrict__ bstart) {
    int t = blockIdx.x * 256 + threadIdx.x;
    if (t < NB) {
        int run = bstart[t];
        for (int b = 0; b < SCB; b++) {
            int idx = b * NB + t;
            int v = hist[idx];
            hist[idx] = run;
            run += v;
        }
    }
}

// scatter edges into exclusive per-(block,bucket) regions via LDS cursors.
// all appends to a region come from ONE block -> lines write-combine in its L2.
__global__ void k_scatter(const int* __restrict__ row, const int* __restrict__ col,
                          const int* __restrict__ hist, u32* __restrict__ ebuf, int E) {
    __shared__ int cur[NB];
    int b = blockIdx.x;
    for (int i = threadIdx.x; i < NB; i += 256) cur[i] = hist[b * NB + i];
    __syncthreads();
    int s = b * EPB, e = min(s + EPB, E);
    for (int i = s + threadIdx.x; i < e; i += 256) {
        int c = col[i];
        int p = atomicAdd(&cur[c >> 6], 1);
        ebuf[p] = ((u32)row[i] << 6) | (u32)(c & 63);  // row<=100K fits 26 bits
    }
}

// ---------------- dense compute ----------------

// m'[node,64] = bf16( (in[node,:]@W) * dinv[node] ).
// If bnStats != nullptr, the staged input is relu(BN(in)) instead of raw in.
template<int K>
__global__ void k_gemm(const float* __restrict__ h, const float* __restrict__ W,
                       const float* __restrict__ dinv, u16* __restrict__ m, int N,
                       const float* __restrict__ bnStats, const float* __restrict__ bnG,
                       const float* __restrict__ bnB) {
    __shared__ float sh[16][K];
    const float invN = 1.0f / (float)N;
    int block0 = blockIdx.x * 16;
    for (int idx = threadIdx.x; idx < 16 * K; idx += 256) {
        int nn = idx / K, kk = idx % K;
        int node = block0 + nn;
        float v = (node < N) ? h[(size_t)node * K + kk] : 0.f;
        if (bnStats) {
            float mean = bnStats[kk] * invN;
            float var = bnStats[K + kk] * invN - mean * mean;
            float sc = bnG[kk] * rsqrtf(var + BN_EPS);
            v = fmaxf((v - mean) * sc + bnB[kk], 0.f);
        }
        sh[nn][kk] = v;
    }
    __syncthreads();
    int colj = threadIdx.x & 63;
    int nl = threadIdx.x >> 6;  // 0..3 (uniform per wave -> LDS broadcast reads)
    float a0 = 0.f, a1 = 0.f, a2 = 0.f, a3 = 0.f;
    #pragma unroll 8
    for (int k = 0; k < K; k++) {
        float w = W[k * HID + colj];  // L1-resident (<=32KB)
        a0 += sh[nl][k] * w;
        a1 += sh[nl + 4][k] * w;
        a2 += sh[nl + 8][k] * w;
        a3 += sh[nl + 12][k] * w;
    }
    int n0 = block0 + nl;
    if (n0 < N)      m[(size_t)n0 * HID + colj]        = f2bf(a0 * dinv[n0]);
    if (n0 + 4 < N)  m[(size_t)(n0 + 4) * HID + colj]  = f2bf(a1 * dinv[n0 + 4]);
    if (n0 + 8 < N)  m[(size_t)(n0 + 8) * HID + colj]  = f2bf(a2 * dinv[n0 + 8]);
    if (n0 + 12 < N) m[(size_t)(n0 + 12) * HID + colj] = f2bf(a3 * dinv[n0 + 12]);
}

// gemm3 staging computes h2 = relu( BN2(agg2) + relu(BN1(agg1)) ) on the fly.
__global__ void k_gemm3(const float* __restrict__ agg1, const float* __restrict__ agg2,
                        const float* __restrict__ st1, const float* __restrict__ st2,
                        const float* __restrict__ g1, const float* __restrict__ be1,
                        const float* __restrict__ g2, const float* __restrict__ be2,
                        const float* __restrict__ W, const float* __restrict__ dinv,
                        u16* __restrict__ m, int N) {
    __shared__ float sh[16][HID];
    const float invN = 1.0f / (float)N;
    int block0 = blockIdx.x * 16;
    for (int idx = threadIdx.x; idx < 16 * HID; idx += 256) {
        int nn = idx / HID, kk = idx % HID;
        int node = block0 + nn;
        float v = 0.f;
        if (node < N) {
            size_t p = (size_t)node * HID + kk;
            float m1 = st1[kk] * invN;
            float v1 = st1[64 + kk] * invN - m1 * m1;
            float s1 = g1[kk] * rsqrtf(v1 + BN_EPS);
            float h1 = fmaxf((agg1[p] - m1) * s1 + be1[kk], 0.f);
            float m2 = st2[kk] * invN;
            float v2 = st2[64 + kk] * invN - m2 * m2;
            float s2 = g2[kk] * rsqrtf(v2 + BN_EPS);
            v = fmaxf((agg2[p] - m2) * s2 + be2[kk] + h1, 0.f);
        }
        sh[nn][kk] = v;
    }
    __syncthreads();
    int colj = threadIdx.x & 63;
    int nl = threadIdx.x >> 6;
    float a0 = 0.f, a1 = 0.f, a2 = 0.f, a3 = 0.f;
    #pragma unroll 8
    for (int k = 0; k < HID; k++) {
        float w = W[k * HID + colj];
        a0 += sh[nl][k] * w;
        a1 += sh[nl + 4][k] * w;
        a2 += sh[nl + 8][k] * w;
        a3 += sh[nl + 12][k] * w;
    }
    int n0 = block0 + nl;
    if (n0 < N)      m[(size_t)n0 * HID + colj]        = f2bf(a0 * dinv[n0]);
    if (n0 + 4 < N)  m[(size_t)(n0 + 4) * HID + colj]  = f2bf(a1 * dinv[n0 + 4]);
    if (n0 + 8 < N)  m[(size_t)(n0 + 8) * HID + colj]  = f2bf(a2 * dinv[n0 + 8]);
    if (n0 + 12 < N) m[(size_t)(n0 + 12) * HID + colj] = f2bf(a3 * dinv[n0 + 12]);
}

// fused aggregation: one block per bucket (64 target nodes, 256 thr = 4 waves).
// builds an LDS CSR from the bucketized segment, then per-node-wave gather
// (full node parallelism), dinv scale, agg write, fused BN-stats reduction.
__global__ void __launch_bounds__(256)
k_fusedagg(const u16* __restrict__ m, const float* __restrict__ dinv,
           const u32* __restrict__ ebuf, const int* __restrict__ bstart,
           float* __restrict__ agg, float* __restrict__ stats, int N) {
    __shared__ u32 seg[SEGCAP];
    __shared__ u32 lrows[SEGCAP];
    __shared__ int lcnt[64], lstart[64], lcur[64];
    __shared__ float rs[4][64], rq[4][64];
    int b = blockIdx.x, t = threadIdx.x;
    int lane = t & 63, w = t >> 6;
    int s = bstart[b];
    int cnt = min(bstart[b + 1] - s, SEGCAP);
    if (t < 64) { lcnt[t] = 0; lcur[t] = 0; }
    __syncthreads();
    for (int i = t; i < cnt; i += 256) {
        u32 v = ebuf[s + i];
        seg[i] = v;
        atomicAdd(&lcnt[v & 63u], 1);
    }
    __syncthreads();
    if (w == 0) {  // wave-wide exclusive scan of 64 counts
        int v = lcnt[lane];
        int x = v;
        for (int o = 1; o < 64; o <<= 1) {
            int y = __shfl_up(x, o, 64);
            if (lane >= o) x += y;
        }
        lstart[lane] = x - v;
    }
    __syncthreads();
    for (int i = t; i < cnt; i += 256) {
        u32 v = seg[i];
        int c = (int)(v & 63u);
        int p = lstart[c] + atomicAdd(&lcur[c], 1);
        lrows[p] = v >> 6;
    }
    __syncthreads();
    int node0 = b * 64;
    float sum = 0.f, sq = 0.f;
    for (int i = 0; i < 16; i++) {
        int c = w * 16 + i;
        int node = node0 + c;
        if (node < N) {
            float acc = bf2f(m[(size_t)node * HID + lane]);  // self-loop message
            int ls = lstart[c], le = ls + lcnt[c];
            #pragma unroll 4
            for (int j = ls; j < le; j++) {
                int r = (int)lrows[j];
                acc += bf2f(m[(size_t)r * HID + lane]);
            }
            float v = acc * dinv[node];
            agg[(size_t)node * HID + lane] = v;
            sum += v; sq += v * v;
        }
    }
    rs[w][lane] = sum; rq[w][lane] = sq;
    __syncthreads();
    if (w == 0) {
        float a = rs[0][lane] + rs[1][lane] + rs[2][lane] + rs[3][lane];
        float q = rq[0][lane] + rq[1][lane] + rq[2][lane] + rq[3][lane];
        atomicAdd(&stats[lane], a);
        atomicAdd(&stats[64 + lane], q);
    }
}

// sorted-batch run-length pooling with BN3+relu applied inline.
__global__ void k_pool(const float* __restrict__ agg3, const float* __restrict__ st3,
                       const float* __restrict__ g3, const float* __restrict__ be3,
                       const int* __restrict__ batch, float* __restrict__ pooled,
                       float* __restrict__ gcnt, int N) {
    int lane = threadIdx.x;  // blockDim = 64
    int start = blockIdx.x * 64;
    if (start >= N) return;
    const float invN = 1.0f / (float)N;
    float mean = st3[lane] * invN;
    float var = st3[64 + lane] * invN - mean * mean;
    float sc = g3[lane] * rsqrtf(var + BN_EPS);
    float bb = be3[lane];
    int end = min(start + 64, N);
    int gcur = batch[start];
    float acc = 0.f; int run = 0;
    for (int n = start; n < end; n++) {
        int g = batch[n];
        if (g != gcur) {
            atomicAdd(&pooled[gcur * HID + lane], acc);
            if (lane == 0) atomicAdd(&gcnt[gcur], (float)run);
            acc = 0.f; run = 0; gcur = g;
        }
        acc += fmaxf((agg3[(size_t)n * HID + lane] - mean) * sc + bb, 0.f);
        run++;
    }
    atomicAdd(&pooled[gcur * HID + lane], acc);
    if (lane == 0) atomicAdd(&gcnt[gcur], (float)run);
}

// out[g] = dot(pooled[g]/max(cnt,1), fcw) + fcb.  wave per graph.
__global__ void k_final(const float* __restrict__ pooled, const float* __restrict__ gcnt,
                        const float* __restrict__ fcw, const float* __restrict__ fcb,
                        float* __restrict__ out) {
    int g = (int)((blockIdx.x * (size_t)blockDim.x + threadIdx.x) >> 6);
    int lane = threadIdx.x & 63;
    if (g >= NG) return;
    float c = fmaxf(gcnt[g], 1.f);
    float v = pooled[g * HID + lane] / c * fcw[lane];
    for (int off = 32; off > 0; off >>= 1) v += __shfl_down(v, off, 64);
    if (lane == 0) out[g] = v + fcb[0];
}

// ---------------- launch ----------------

extern "C" void kernel_launch(void* const* d_in, const int* in_sizes, int n_in,
                              void* d_out, int out_size, void* d_ws, size_t ws_size,
                              hipStream_t stream) {
    const float* x    = (const float*)d_in[0];
    const int*   ei   = (const int*)d_in[1];
    const int*   batch= (const int*)d_in[2];
    const float* w1   = (const float*)d_in[3];
    const float* g1   = (const float*)d_in[5];
    const float* be1  = (const float*)d_in[6];
    const float* w2   = (const float*)d_in[7];
    const float* g2   = (const float*)d_in[9];
    const float* be2  = (const float*)d_in[10];
    const float* w3   = (const float*)d_in[11];
    const float* g3   = (const float*)d_in[13];
    const float* be3  = (const float*)d_in[14];
    const float* fcw  = (const float*)d_in[15];
    const float* fcb  = (const float*)d_in[16];
    float* out = (float*)d_out;

    const int N = NN, E = NE;
    const int* erow = ei;       // edge_index[0] = source
    const int* ecol = ei + E;   // edge_index[1] = target

    char* ws = (char*)d_ws;
    size_t off = 0;
    auto alloc = [&](size_t bytes) -> char* {
        char* p = ws + off;
        off = (off + bytes + 255) & ~(size_t)255;
        return p;
    };
    int*   deg    = (int*)alloc((size_t)N * 4);
    float* dinv   = (float*)alloc((size_t)N * 4);
    int*   hist   = (int*)alloc((size_t)SCB * NB * 4);   // per-block bucket bases
    int*   bcnt   = (int*)alloc((size_t)NB * 4);
    int*   bstart = (int*)alloc((size_t)(NB + 1) * 4);
    u32*   ebuf   = (u32*)alloc((size_t)E * 4);          // bucketized packed edges
    u16*   bufM   = (u16*)alloc((size_t)N * HID * 2);    // m' (bf16, dinv-scaled)
    float* aggB1  = (float*)alloc((size_t)N * HID * 4);  // agg1, reused as agg3
    float* aggB2  = (float*)alloc((size_t)N * HID * 4);  // agg2
    float* stats  = (float*)alloc(3 * 128 * 4);
    float* pooled = (float*)alloc((size_t)NG * HID * 4);
    float* gcnt   = (float*)alloc((size_t)NG * 4);
    (void)ws_size; (void)in_sizes; (void)n_in; (void)out_size;

    float* aggB3 = aggB1;  // agg1 last read in k_gemm3, before layer-3 agg

    hipMemsetAsync(deg, 0, (size_t)N * 4, stream);
    hipMemsetAsync(stats, 0, 3 * 128 * 4, stream);
    hipMemsetAsync(pooled, 0, (size_t)NG * HID * 4, stream);
    hipMemsetAsync(gcnt, 0, (size_t)NG * 4, stream);

    const int nbN = (N + 255) / 256;       // 391
    const int nbNode16 = (N + 15) / 16;    // 6250
    const int nbB = (NB + 255) / 256;      // 7

    // graph build: multisplit with private regions
    k_hist<<<SCB, 256, 0, stream>>>(ecol, hist, deg, E);
    k_dinv<<<nbN, 256, 0, stream>>>(deg, dinv, N);
    k_btot<<<nbB, 256, 0, stream>>>(hist, bcnt);
    k_bscan<<<1, 256, 0, stream>>>(bcnt, bstart, NB, E);
    k_hcol<<<nbB, 256, 0, stream>>>(hist, bstart);
    k_scatter<<<SCB, 256, 0, stream>>>(erow, ecol, hist, ebuf, E);

    // layer 1
    k_gemm<INDIM><<<nbNode16, 256, 0, stream>>>(x, w1, dinv, bufM, N,
                                                nullptr, nullptr, nullptr);
    k_fusedagg<<<NB, 256, 0, stream>>>(bufM, dinv, ebuf, bstart, aggB1, stats, N);

    // layer 2 (gemm stages relu(BN1(agg1)))
    k_gemm<HID><<<nbNode16, 256, 0, stream>>>(aggB1, w2, dinv, bufM, N,
                                              stats, g1, be1);
    k_fusedagg<<<NB, 256, 0, stream>>>(bufM, dinv, ebuf, bstart, aggB2, stats + 128, N);

    // layer 3 (gemm stages h2 = relu(BN2(agg2) + relu(BN1(agg1))))
    k_gemm3<<<nbNode16, 256, 0, stream>>>(aggB1, aggB2, stats, stats + 128,
                                          g1, be1, g2, be2, w3, dinv, bufM, N);
    k_fusedagg<<<NB, 256, 0, stream>>>(bufM, dinv, ebuf, bstart, aggB3, stats + 256, N);

    // pool (BN3+relu inline) + final
    k_pool<<<(N + 63) / 64, 64, 0, stream>>>(aggB3, stats + 256, g3, be3,
                                             batch, pooled, gcnt, N);
    k_final<<<(NG * 64) / 256, 256, 0, stream>>>(pooled, gcnt, fcw, fcb, out);
}

// Round 7
// 512.639 us; speedup vs baseline: 4.8756x; 1.2448x over previous
//
#include <hip/hip_runtime.h>

#define NN 100000
#define NE 1600000
#define INDIM 128
#define HID 64
#define NG 1024
#define NB 1563            // ceil(NN/64) buckets of 64 target nodes
#define SCB 256            // scatter blocks (private-region multisplit)
#define EPB ((NE + SCB - 1) / SCB)   // 6250 edges per scatter block
#define SEGCAP 2048        // max edges per bucket (avg 1024; generous margin)
#define BN_EPS 1e-5f

typedef unsigned short u16;
typedef unsigned int u32;

__device__ __forceinline__ u16 f2bf(float f) {
    u32 u = __float_as_uint(f);
    u32 r = (u + 0x7fffu + ((u >> 16) & 1u)) >> 16;   // RNE
    return (u16)r;
}
__device__ __forceinline__ float bf2f(u32 b) {
    return __uint_as_float(b << 16);
}

// ---------------- graph preprocessing ----------------

// per-block bucket histogram (LDS only; no per-node deg atomics).
__global__ void k_hist(const int* __restrict__ col, int* __restrict__ hist, int E) {
    __shared__ int h[NB];
    int b = blockIdx.x;
    for (int i = threadIdx.x; i < NB; i += 256) h[i] = 0;
    __syncthreads();
    int s = b * EPB, e = min(s + EPB, E);
    for (int i = s + threadIdx.x; i < e; i += 256) {
        atomicAdd(&h[col[i] >> 6], 1);
    }
    __syncthreads();
    for (int i = threadIdx.x; i < NB; i += 256) hist[b * NB + i] = h[i];
}

// bucket totals: bcnt[bucket] = sum over scatter blocks (coalesced per iteration).
__global__ void k_btot(const int* __restrict__ hist, int* __restrict__ bcnt) {
    int t = blockIdx.x * 256 + threadIdx.x;
    if (t < NB) {
        int s = 0;
        for (int b = 0; b < SCB; b++) s += hist[b * NB + t];
        bcnt[t] = s;
    }
}

// exclusive scan of bcnt[NB] -> bstart (single block, 256 thr x 7 items).
__global__ void k_bscan(const int* __restrict__ bcnt, int* __restrict__ bstart, int B, int E) {
    __shared__ int ts[256];
    int t = threadIdx.x;
    int loc[7];
    int s = 0;
    for (int i = 0; i < 7; i++) {
        int idx = t * 7 + i;
        loc[i] = (idx < B) ? bcnt[idx] : 0;
        s += loc[i];
    }
    ts[t] = s;
    __syncthreads();
    for (int off = 1; off < 256; off <<= 1) {
        int add = (t >= off) ? ts[t - off] : 0;
        __syncthreads();
        ts[t] += add;
        __syncthreads();
    }
    int ex = ts[t] - s;
    for (int i = 0; i < 7; i++) {
        int idx = t * 7 + i;
        if (idx < B) bstart[idx] = ex;
        ex += loc[i];
    }
    if (t == 0) bstart[B] = E;
}

// convert hist[block][bucket] into absolute write bases.
__global__ void k_hcol(int* __restrict__ hist, const int* __restrict__ bstart) {
    int t = blockIdx.x * 256 + threadIdx.x;
    if (t < NB) {
        int run = bstart[t];
        for (int b = 0; b < SCB; b++) {
            int idx = b * NB + t;
            int v = hist[idx];
            hist[idx] = run;
            run += v;
        }
    }
}

// scatter edges into exclusive per-(block,bucket) regions via LDS cursors.
__global__ void k_scatter(const int* __restrict__ row, const int* __restrict__ col,
                          const int* __restrict__ hist, u32* __restrict__ ebuf, int E) {
    __shared__ int cur[NB];
    int b = blockIdx.x;
    for (int i = threadIdx.x; i < NB; i += 256) cur[i] = hist[b * NB + i];
    __syncthreads();
    int s = b * EPB, e = min(s + EPB, E);
    for (int i = s + threadIdx.x; i < e; i += 256) {
        int c = col[i];
        int p = atomicAdd(&cur[c >> 6], 1);
        ebuf[p] = ((u32)row[i] << 6) | (u32)(c & 63);  // row<2^17 fits
    }
}

// dinv from bucketized edges: LDS counts, sequential writes, no global atomics.
__global__ void k_degb(const u32* __restrict__ ebuf, const int* __restrict__ bstart,
                       float* __restrict__ dinv, int N) {
    __shared__ int lcnt[64];
    int b = blockIdx.x, t = threadIdx.x;
    if (t < 64) lcnt[t] = 0;
    __syncthreads();
    int s = bstart[b], e = bstart[b + 1];
    for (int i = s + t; i < e; i += 256) {
        atomicAdd(&lcnt[ebuf[i] & 63u], 1);
    }
    __syncthreads();
    if (t < 64) {
        int node = b * 64 + t;
        if (node < N) dinv[node] = rsqrtf((float)(lcnt[t] + 1));  // +1 self-loop
    }
}

// ---------------- dense compute ----------------

// m'[node,64] = bf16( (in[node,:]@W) * dinv[node] ).
// If bnStats != nullptr, the staged input is relu(BN(in)) instead of raw in.
template<int K>
__global__ void k_gemm(const float* __restrict__ h, const float* __restrict__ W,
                       const float* __restrict__ dinv, u16* __restrict__ m, int N,
                       const float* __restrict__ bnStats, const float* __restrict__ bnG,
                       const float* __restrict__ bnB) {
    __shared__ float sh[16][K];
    const float invN = 1.0f / (float)N;
    int block0 = blockIdx.x * 16;
    for (int idx = threadIdx.x; idx < 16 * K; idx += 256) {
        int nn = idx / K, kk = idx % K;
        int node = block0 + nn;
        float v = (node < N) ? h[(size_t)node * K + kk] : 0.f;
        if (bnStats) {
            float mean = bnStats[kk] * invN;
            float var = bnStats[K + kk] * invN - mean * mean;
            float sc = bnG[kk] * rsqrtf(var + BN_EPS);
            v = fmaxf((v - mean) * sc + bnB[kk], 0.f);
        }
        sh[nn][kk] = v;
    }
    __syncthreads();
    int colj = threadIdx.x & 63;
    int nl = threadIdx.x >> 6;  // 0..3 (uniform per wave -> LDS broadcast reads)
    float a0 = 0.f, a1 = 0.f, a2 = 0.f, a3 = 0.f;
    #pragma unroll 8
    for (int k = 0; k < K; k++) {
        float w = W[k * HID + colj];  // L1-resident (<=32KB)
        a0 += sh[nl][k] * w;
        a1 += sh[nl + 4][k] * w;
        a2 += sh[nl + 8][k] * w;
        a3 += sh[nl + 12][k] * w;
    }
    int n0 = block0 + nl;
    if (n0 < N)      m[(size_t)n0 * HID + colj]        = f2bf(a0 * dinv[n0]);
    if (n0 + 4 < N)  m[(size_t)(n0 + 4) * HID + colj]  = f2bf(a1 * dinv[n0 + 4]);
    if (n0 + 8 < N)  m[(size_t)(n0 + 8) * HID + colj]  = f2bf(a2 * dinv[n0 + 8]);
    if (n0 + 12 < N) m[(size_t)(n0 + 12) * HID + colj] = f2bf(a3 * dinv[n0 + 12]);
}

// gemm3 staging computes h2 = relu( BN2(agg2) + relu(BN1(agg1)) ) on the fly.
__global__ void k_gemm3(const float* __restrict__ agg1, const float* __restrict__ agg2,
                        const float* __restrict__ st1, const float* __restrict__ st2,
                        const float* __restrict__ g1, const float* __restrict__ be1,
                        const float* __restrict__ g2, const float* __restrict__ be2,
                        const float* __restrict__ W, const float* __restrict__ dinv,
                        u16* __restrict__ m, int N) {
    __shared__ float sh[16][HID];
    const float invN = 1.0f / (float)N;
    int block0 = blockIdx.x * 16;
    for (int idx = threadIdx.x; idx < 16 * HID; idx += 256) {
        int nn = idx / HID, kk = idx % HID;
        int node = block0 + nn;
        float v = 0.f;
        if (node < N) {
            size_t p = (size_t)node * HID + kk;
            float m1 = st1[kk] * invN;
            float v1 = st1[64 + kk] * invN - m1 * m1;
            float s1 = g1[kk] * rsqrtf(v1 + BN_EPS);
            float h1 = fmaxf((agg1[p] - m1) * s1 + be1[kk], 0.f);
            float m2 = st2[kk] * invN;
            float v2 = st2[64 + kk] * invN - m2 * m2;
            float s2 = g2[kk] * rsqrtf(v2 + BN_EPS);
            v = fmaxf((agg2[p] - m2) * s2 + be2[kk] + h1, 0.f);
        }
        sh[nn][kk] = v;
    }
    __syncthreads();
    int colj = threadIdx.x & 63;
    int nl = threadIdx.x >> 6;
    float a0 = 0.f, a1 = 0.f, a2 = 0.f, a3 = 0.f;
    #pragma unroll 8
    for (int k = 0; k < HID; k++) {
        float w = W[k * HID + colj];
        a0 += sh[nl][k] * w;
        a1 += sh[nl + 4][k] * w;
        a2 += sh[nl + 8][k] * w;
        a3 += sh[nl + 12][k] * w;
    }
    int n0 = block0 + nl;
    if (n0 < N)      m[(size_t)n0 * HID + colj]        = f2bf(a0 * dinv[n0]);
    if (n0 + 4 < N)  m[(size_t)(n0 + 4) * HID + colj]  = f2bf(a1 * dinv[n0 + 4]);
    if (n0 + 8 < N)  m[(size_t)(n0 + 8) * HID + colj]  = f2bf(a2 * dinv[n0 + 8]);
    if (n0 + 12 < N) m[(size_t)(n0 + 12) * HID + colj] = f2bf(a3 * dinv[n0 + 12]);
}

// fused aggregation v2: one block per bucket (64 nodes, 4 waves).
// LDS CSR build, then per-node gather with a row spread over 16 lanes (uint2 =
// 4 bf16 features/lane) -> 4 rows in flight per wave, trip count /4.
__global__ void __launch_bounds__(256)
k_fusedagg(const u16* __restrict__ m, const float* __restrict__ dinv,
           const u32* __restrict__ ebuf, const int* __restrict__ bstart,
           float* __restrict__ agg, float* __restrict__ stats, int N) {
    __shared__ u32 seg[SEGCAP];
    __shared__ u32 lrows[SEGCAP];
    __shared__ int lcnt[64], lstart[64], lcur[64];
    __shared__ float rs[4][64], rq[4][64];
    int b = blockIdx.x, t = threadIdx.x;
    int lane = t & 63, w = t >> 6;
    int s = bstart[b];
    int cnt = min(bstart[b + 1] - s, SEGCAP);
    if (t < 64) { lcnt[t] = 0; lcur[t] = 0; }
    __syncthreads();
    for (int i = t; i < cnt; i += 256) {
        u32 v = ebuf[s + i];
        seg[i] = v;
        atomicAdd(&lcnt[v & 63u], 1);
    }
    __syncthreads();
    if (w == 0) {  // wave-wide exclusive scan of 64 counts
        int v = lcnt[lane];
        int x = v;
        for (int o = 1; o < 64; o <<= 1) {
            int y = __shfl_up(x, o, 64);
            if (lane >= o) x += y;
        }
        lstart[lane] = x - v;
    }
    __syncthreads();
    for (int i = t; i < cnt; i += 256) {
        u32 v = seg[i];
        int c = (int)(v & 63u);
        int p = lstart[c] + atomicAdd(&lcur[c], 1);
        lrows[p] = v >> 6;
    }
    __syncthreads();
    int node0 = b * 64;
    int g = lane >> 4;       // edge group 0..3
    int sub = lane & 15;     // feature quad: features sub*4 .. sub*4+3
    float ssum0 = 0.f, ssum1 = 0.f, ssum2 = 0.f, ssum3 = 0.f;
    float ssq0 = 0.f, ssq1 = 0.f, ssq2 = 0.f, ssq3 = 0.f;
    for (int i = 0; i < 16; i++) {
        int c = w * 16 + i;
        int node = node0 + c;
        if (node >= N) continue;
        float a0 = 0.f, a1 = 0.f, a2 = 0.f, a3 = 0.f;
        if (g == 0) {  // self-loop message (added by group 0 only)
            uint2 v = ((const uint2*)(m + ((size_t)node << 6)))[sub];
            a0 = bf2f(v.x & 0xffffu); a1 = bf2f(v.x >> 16);
            a2 = bf2f(v.y & 0xffffu); a3 = bf2f(v.y >> 16);
        }
        int ls = lstart[c], cntc = lcnt[c];
        #pragma unroll 2
        for (int k = g; k < cntc; k += 4) {
            int r = (int)lrows[ls + k];
            uint2 v = ((const uint2*)(m + ((size_t)r << 6)))[sub];
            a0 += bf2f(v.x & 0xffffu); a1 += bf2f(v.x >> 16);
            a2 += bf2f(v.y & 0xffffu); a3 += bf2f(v.y >> 16);
        }
        // reduce across the 4 edge groups (lanes sub, sub+16, sub+32, sub+48)
        a0 += __shfl_xor(a0, 16, 64); a0 += __shfl_xor(a0, 32, 64);
        a1 += __shfl_xor(a1, 16, 64); a1 += __shfl_xor(a1, 32, 64);
        a2 += __shfl_xor(a2, 16, 64); a2 += __shfl_xor(a2, 32, 64);
        a3 += __shfl_xor(a3, 16, 64); a3 += __shfl_xor(a3, 32, 64);
        if (lane < 16) {
            float di = dinv[node];
            float v0 = a0 * di, v1 = a1 * di, v2 = a2 * di, v3 = a3 * di;
            *(float4*)(agg + ((size_t)node << 6) + sub * 4) =
                make_float4(v0, v1, v2, v3);
            ssum0 += v0; ssum1 += v1; ssum2 += v2; ssum3 += v3;
            ssq0 += v0 * v0; ssq1 += v1 * v1; ssq2 += v2 * v2; ssq3 += v3 * v3;
        }
    }
    if (lane < 16) {
        rs[w][sub * 4 + 0] = ssum0; rs[w][sub * 4 + 1] = ssum1;
        rs[w][sub * 4 + 2] = ssum2; rs[w][sub * 4 + 3] = ssum3;
        rq[w][sub * 4 + 0] = ssq0; rq[w][sub * 4 + 1] = ssq1;
        rq[w][sub * 4 + 2] = ssq2; rq[w][sub * 4 + 3] = ssq3;
    }
    __syncthreads();
    if (w == 0) {
        float a = rs[0][lane] + rs[1][lane] + rs[2][lane] + rs[3][lane];
        float q = rq[0][lane] + rq[1][lane] + rq[2][lane] + rq[3][lane];
        atomicAdd(&stats[lane], a);
        atomicAdd(&stats[64 + lane], q);
    }
}

// sorted-batch run-length pooling with BN3+relu applied inline.
__global__ void k_pool(const float* __restrict__ agg3, const float* __restrict__ st3,
                       const float* __restrict__ g3, const float* __restrict__ be3,
                       const int* __restrict__ batch, float* __restrict__ pooled,
                       float* __restrict__ gcnt, int N) {
    int lane = threadIdx.x;  // blockDim = 64
    int start = blockIdx.x * 64;
    if (start >= N) return;
    const float invN = 1.0f / (float)N;
    float mean = st3[lane] * invN;
    float var = st3[64 + lane] * invN - mean * mean;
    float sc = g3[lane] * rsqrtf(var + BN_EPS);
    float bb = be3[lane];
    int end = min(start + 64, N);
    int gcur = batch[start];
    float acc = 0.f; int run = 0;
    for (int n = start; n < end; n++) {
        int g = batch[n];
        if (g != gcur) {
            atomicAdd(&pooled[gcur * HID + lane], acc);
            if (lane == 0) atomicAdd(&gcnt[gcur], (float)run);
            acc = 0.f; run = 0; gcur = g;
        }
        acc += fmaxf((agg3[(size_t)n * HID + lane] - mean) * sc + bb, 0.f);
        run++;
    }
    atomicAdd(&pooled[gcur * HID + lane], acc);
    if (lane == 0) atomicAdd(&gcnt[gcur], (float)run);
}

// out[g] = dot(pooled[g]/max(cnt,1), fcw) + fcb.  wave per graph.
__global__ void k_final(const float* __restrict__ pooled, const float* __restrict__ gcnt,
                        const float* __restrict__ fcw, const float* __restrict__ fcb,
                        float* __restrict__ out) {
    int g = (int)((blockIdx.x * (size_t)blockDim.x + threadIdx.x) >> 6);
    int lane = threadIdx.x & 63;
    if (g >= NG) return;
    float c = fmaxf(gcnt[g], 1.f);
    float v = pooled[g * HID + lane] / c * fcw[lane];
    for (int off = 32; off > 0; off >>= 1) v += __shfl_down(v, off, 64);
    if (lane == 0) out[g] = v + fcb[0];
}

// ---------------- launch ----------------

extern "C" void kernel_launch(void* const* d_in, const int* in_sizes, int n_in,
                              void* d_out, int out_size, void* d_ws, size_t ws_size,
                              hipStream_t stream) {
    const float* x    = (const float*)d_in[0];
    const int*   ei   = (const int*)d_in[1];
    const int*   batch= (const int*)d_in[2];
    const float* w1   = (const float*)d_in[3];
    const float* g1   = (const float*)d_in[5];
    const float* be1  = (const float*)d_in[6];
    const float* w2   = (const float*)d_in[7];
    const float* g2   = (const float*)d_in[9];
    const float* be2  = (const float*)d_in[10];
    const float* w3   = (const float*)d_in[11];
    const float* g3   = (const float*)d_in[13];
    const float* be3  = (const float*)d_in[14];
    const float* fcw  = (const float*)d_in[15];
    const float* fcb  = (const float*)d_in[16];
    float* out = (float*)d_out;

    const int N = NN, E = NE;
    const int* erow = ei;       // edge_index[0] = source
    const int* ecol = ei + E;   // edge_index[1] = target

    char* ws = (char*)d_ws;
    size_t off = 0;
    auto alloc = [&](size_t bytes) -> char* {
        char* p = ws + off;
        off = (off + bytes + 255) & ~(size_t)255;
        return p;
    };
    float* dinv   = (float*)alloc((size_t)N * 4);
    int*   hist   = (int*)alloc((size_t)SCB * NB * 4);   // per-block bucket bases
    int*   bcnt   = (int*)alloc((size_t)NB * 4);
    int*   bstart = (int*)alloc((size_t)(NB + 1) * 4);
    u32*   ebuf   = (u32*)alloc((size_t)E * 4);          // bucketized packed edges
    u16*   bufM   = (u16*)alloc((size_t)N * HID * 2);    // m' (bf16, dinv-scaled)
    float* aggB1  = (float*)alloc((size_t)N * HID * 4);  // agg1, reused as agg3
    float* aggB2  = (float*)alloc((size_t)N * HID * 4);  // agg2
    float* stats  = (float*)alloc(3 * 128 * 4);
    float* pooled = (float*)alloc((size_t)NG * HID * 4);
    float* gcnt   = (float*)alloc((size_t)NG * 4);
    (void)ws_size; (void)in_sizes; (void)n_in; (void)out_size;

    float* aggB3 = aggB1;  // agg1 last read in k_gemm3, before layer-3 agg

    hipMemsetAsync(stats, 0, 3 * 128 * 4, stream);
    hipMemsetAsync(pooled, 0, (size_t)NG * HID * 4, stream);
    hipMemsetAsync(gcnt, 0, (size_t)NG * 4, stream);

    const int nbNode16 = (N + 15) / 16;    // 6250
    const int nbB = (NB + 255) / 256;      // 7

    // graph build: multisplit with private regions
    k_hist<<<SCB, 256, 0, stream>>>(ecol, hist, E);
    k_btot<<<nbB, 256, 0, stream>>>(hist, bcnt);
    k_bscan<<<1, 256, 0, stream>>>(bcnt, bstart, NB, E);
    k_hcol<<<nbB, 256, 0, stream>>>(hist, bstart);
    k_scatter<<<SCB, 256, 0, stream>>>(erow, ecol, hist, ebuf, E);
    k_degb<<<NB, 256, 0, stream>>>(ebuf, bstart, dinv, N);

    // layer 1
    k_gemm<INDIM><<<nbNode16, 256, 0, stream>>>(x, w1, dinv, bufM, N,
                                                nullptr, nullptr, nullptr);
    k_fusedagg<<<NB, 256, 0, stream>>>(bufM, dinv, ebuf, bstart, aggB1, stats, N);

    // layer 2 (gemm stages relu(BN1(agg1)))
    k_gemm<HID><<<nbNode16, 256, 0, stream>>>(aggB1, w2, dinv, bufM, N,
                                              stats, g1, be1);
    k_fusedagg<<<NB, 256, 0, stream>>>(bufM, dinv, ebuf, bstart, aggB2, stats + 128, N);

    // layer 3 (gemm stages h2 = relu(BN2(agg2) + relu(BN1(agg1))))
    k_gemm3<<<nbNode16, 256, 0, stream>>>(aggB1, aggB2, stats, stats + 128,
                                          g1, be1, g2, be2, w3, dinv, bufM, N);
    k_fusedagg<<<NB, 256, 0, stream>>>(bufM, dinv, ebuf, bstart, aggB3, stats + 256, N);

    // pool (BN3+relu inline) + final
    k_pool<<<(N + 63) / 64, 64, 0, stream>>>(aggB3, stats + 256, g3, be3,
                                             batch, pooled, gcnt, N);
    k_final<<<(NG * 64) / 256, 256, 0, stream>>>(pooled, gcnt, fcw, fcb, out);
}

// Round 8
// 503.168 us; speedup vs baseline: 4.9674x; 1.0188x over previous
//
#include <hip/hip_runtime.h>

#define NN 100000
#define NE 1600000
#define INDIM 128
#define HID 64
#define NG 1024
#define NB 1563            // ceil(NN/64) buckets of 64 target nodes
#define SCB 256            // scatter blocks (private-region multisplit)
#define EPB ((NE + SCB - 1) / SCB)   // 6250 edges per scatter block
#define SEGCAP 2048        // max edges per bucket (avg 1024; generous margin)
#define BN_EPS 1e-5f

typedef unsigned short u16;
typedef unsigned int u32;

__device__ __forceinline__ u16 f2bf(float f) {
    u32 u = __float_as_uint(f);
    u32 r = (u + 0x7fffu + ((u >> 16) & 1u)) >> 16;   // RNE
    return (u16)r;
}
__device__ __forceinline__ float bf2f(u32 b) {
    return __uint_as_float(b << 16);
}

// ---------------- graph preprocessing ----------------

// per-block bucket histogram (LDS only; no per-node deg atomics).
__global__ void k_hist(const int* __restrict__ col, int* __restrict__ hist, int E) {
    __shared__ int h[NB];
    int b = blockIdx.x;
    for (int i = threadIdx.x; i < NB; i += 256) h[i] = 0;
    __syncthreads();
    int s = b * EPB, e = min(s + EPB, E);
    for (int i = s + threadIdx.x; i < e; i += 256) {
        atomicAdd(&h[col[i] >> 6], 1);
    }
    __syncthreads();
    for (int i = threadIdx.x; i < NB; i += 256) hist[b * NB + i] = h[i];
}

// bucket totals: bcnt[bucket] = sum over scatter blocks (coalesced per iteration).
__global__ void k_btot(const int* __restrict__ hist, int* __restrict__ bcnt) {
    int t = blockIdx.x * 256 + threadIdx.x;
    if (t < NB) {
        int s = 0;
        for (int b = 0; b < SCB; b++) s += hist[b * NB + t];
        bcnt[t] = s;
    }
}

// exclusive scan of bcnt[NB] -> bstart (single block, 256 thr x 7 items).
__global__ void k_bscan(const int* __restrict__ bcnt, int* __restrict__ bstart, int B, int E) {
    __shared__ int ts[256];
    int t = threadIdx.x;
    int loc[7];
    int s = 0;
    for (int i = 0; i < 7; i++) {
        int idx = t * 7 + i;
        loc[i] = (idx < B) ? bcnt[idx] : 0;
        s += loc[i];
    }
    ts[t] = s;
    __syncthreads();
    for (int off = 1; off < 256; off <<= 1) {
        int add = (t >= off) ? ts[t - off] : 0;
        __syncthreads();
        ts[t] += add;
        __syncthreads();
    }
    int ex = ts[t] - s;
    for (int i = 0; i < 7; i++) {
        int idx = t * 7 + i;
        if (idx < B) bstart[idx] = ex;
        ex += loc[i];
    }
    if (t == 0) bstart[B] = E;
}

// convert hist[block][bucket] into absolute write bases.
__global__ void k_hcol(int* __restrict__ hist, const int* __restrict__ bstart) {
    int t = blockIdx.x * 256 + threadIdx.x;
    if (t < NB) {
        int run = bstart[t];
        for (int b = 0; b < SCB; b++) {
            int idx = b * NB + t;
            int v = hist[idx];
            hist[idx] = run;
            run += v;
        }
    }
}

// scatter edges into exclusive per-(block,bucket) regions via LDS cursors.
__global__ void k_scatter(const int* __restrict__ row, const int* __restrict__ col,
                          const int* __restrict__ hist, u32* __restrict__ ebuf, int E) {
    __shared__ int cur[NB];
    int b = blockIdx.x;
    for (int i = threadIdx.x; i < NB; i += 256) cur[i] = hist[b * NB + i];
    __syncthreads();
    int s = b * EPB, e = min(s + EPB, E);
    for (int i = s + threadIdx.x; i < e; i += 256) {
        int c = col[i];
        int p = atomicAdd(&cur[c >> 6], 1);
        ebuf[p] = ((u32)row[i] << 6) | (u32)(c & 63);  // row<2^17 fits
    }
}

// dinv from bucketized edges: LDS counts, sequential writes, no global atomics.
__global__ void k_degb(const u32* __restrict__ ebuf, const int* __restrict__ bstart,
                       float* __restrict__ dinv, int N) {
    __shared__ int lcnt[64];
    int b = blockIdx.x, t = threadIdx.x;
    if (t < 64) lcnt[t] = 0;
    __syncthreads();
    int s = bstart[b], e = bstart[b + 1];
    for (int i = s + t; i < e; i += 256) {
        atomicAdd(&lcnt[ebuf[i] & 63u], 1);
    }
    __syncthreads();
    if (t < 64) {
        int node = b * 64 + t;
        if (node < N) dinv[node] = rsqrtf((float)(lcnt[t] + 1));  // +1 self-loop
    }
}

// ---------------- dense compute ----------------

// m'[node,64] = bf16( (in[node,:]@W) * dinv[node] ).  float4-staged input.
// If bnStats != nullptr, the staged input is relu(BN(in)) instead of raw in.
template<int K>
__global__ void k_gemm(const float* __restrict__ h, const float* __restrict__ W,
                       const float* __restrict__ dinv, u16* __restrict__ m, int N,
                       const float* __restrict__ bnStats, const float* __restrict__ bnG,
                       const float* __restrict__ bnB) {
    __shared__ float sh[16][K];
    const float invN = 1.0f / (float)N;
    const int K4 = K / 4;                 // float4s per row
    int block0 = blockIdx.x * 16;
    for (int idx = threadIdx.x; idx < 16 * K4; idx += 256) {
        int nn = idx / K4, kk4 = idx % K4;
        int node = block0 + nn;
        float4 v = make_float4(0.f, 0.f, 0.f, 0.f);
        if (node < N) v = *(const float4*)(h + (size_t)node * K + kk4 * 4);
        if (bnStats) {
            #pragma unroll
            for (int j = 0; j < 4; j++) {
                int kk = kk4 * 4 + j;
                float mean = bnStats[kk] * invN;
                float var = bnStats[K + kk] * invN - mean * mean;
                float sc = bnG[kk] * rsqrtf(var + BN_EPS);
                float* pv = (j == 0) ? &v.x : (j == 1) ? &v.y : (j == 2) ? &v.z : &v.w;
                *pv = fmaxf((*pv - mean) * sc + bnB[kk], 0.f);
            }
        }
        *(float4*)(&sh[nn][kk4 * 4]) = v;
    }
    __syncthreads();
    int colj = threadIdx.x & 63;
    int nl = threadIdx.x >> 6;  // 0..3 (uniform per wave -> LDS broadcast reads)
    float a0 = 0.f, a1 = 0.f, a2 = 0.f, a3 = 0.f;
    #pragma unroll 8
    for (int k = 0; k < K; k++) {
        float w = W[k * HID + colj];  // L1-resident (<=32KB)
        a0 += sh[nl][k] * w;
        a1 += sh[nl + 4][k] * w;
        a2 += sh[nl + 8][k] * w;
        a3 += sh[nl + 12][k] * w;
    }
    int n0 = block0 + nl;
    if (n0 < N)      m[(size_t)n0 * HID + colj]        = f2bf(a0 * dinv[n0]);
    if (n0 + 4 < N)  m[(size_t)(n0 + 4) * HID + colj]  = f2bf(a1 * dinv[n0 + 4]);
    if (n0 + 8 < N)  m[(size_t)(n0 + 8) * HID + colj]  = f2bf(a2 * dinv[n0 + 8]);
    if (n0 + 12 < N) m[(size_t)(n0 + 12) * HID + colj] = f2bf(a3 * dinv[n0 + 12]);
}

// gemm3 staging computes h2 = relu( BN2(agg2) + relu(BN1(agg1)) ) on the fly.
__global__ void k_gemm3(const float* __restrict__ agg1, const float* __restrict__ agg2,
                        const float* __restrict__ st1, const float* __restrict__ st2,
                        const float* __restrict__ g1, const float* __restrict__ be1,
                        const float* __restrict__ g2, const float* __restrict__ be2,
                        const float* __restrict__ W, const float* __restrict__ dinv,
                        u16* __restrict__ m, int N) {
    __shared__ float sh[16][HID];
    const float invN = 1.0f / (float)N;
    int block0 = blockIdx.x * 16;
    for (int idx = threadIdx.x; idx < 16 * 16; idx += 256) {   // 16 float4 per row
        int nn = idx / 16, kk4 = idx % 16;
        int node = block0 + nn;
        float4 o = make_float4(0.f, 0.f, 0.f, 0.f);
        if (node < N) {
            size_t p = (size_t)node * HID + kk4 * 4;
            float4 v1 = *(const float4*)(agg1 + p);
            float4 v2 = *(const float4*)(agg2 + p);
            float* p1 = &v1.x; float* p2 = &v2.x; float* po = &o.x;
            #pragma unroll
            for (int j = 0; j < 4; j++) {
                int kk = kk4 * 4 + j;
                float m1 = st1[kk] * invN;
                float va1 = st1[64 + kk] * invN - m1 * m1;
                float s1 = g1[kk] * rsqrtf(va1 + BN_EPS);
                float h1 = fmaxf((p1[j] - m1) * s1 + be1[kk], 0.f);
                float m2 = st2[kk] * invN;
                float va2 = st2[64 + kk] * invN - m2 * m2;
                float s2 = g2[kk] * rsqrtf(va2 + BN_EPS);
                po[j] = fmaxf((p2[j] - m2) * s2 + be2[kk] + h1, 0.f);
            }
        }
        *(float4*)(&sh[nn][kk4 * 4]) = o;
    }
    __syncthreads();
    int colj = threadIdx.x & 63;
    int nl = threadIdx.x >> 6;
    float a0 = 0.f, a1 = 0.f, a2 = 0.f, a3 = 0.f;
    #pragma unroll 8
    for (int k = 0; k < HID; k++) {
        float w = W[k * HID + colj];
        a0 += sh[nl][k] * w;
        a1 += sh[nl + 4][k] * w;
        a2 += sh[nl + 8][k] * w;
        a3 += sh[nl + 12][k] * w;
    }
    int n0 = block0 + nl;
    if (n0 < N)      m[(size_t)n0 * HID + colj]        = f2bf(a0 * dinv[n0]);
    if (n0 + 4 < N)  m[(size_t)(n0 + 4) * HID + colj]  = f2bf(a1 * dinv[n0 + 4]);
    if (n0 + 8 < N)  m[(size_t)(n0 + 8) * HID + colj]  = f2bf(a2 * dinv[n0 + 8]);
    if (n0 + 12 < N) m[(size_t)(n0 + 12) * HID + colj] = f2bf(a3 * dinv[n0 + 12]);
}

// fused aggregation v3: one block per bucket (64 nodes, 4 waves).
// LDS CSR build, then per-node gather with a row spread over 8 lanes (uint4 =
// 8 bf16 features/lane) -> 8 rows in flight per wave (2x MLP vs v2).
__global__ void __launch_bounds__(256)
k_fusedagg(const u16* __restrict__ m, const float* __restrict__ dinv,
           const u32* __restrict__ ebuf, const int* __restrict__ bstart,
           float* __restrict__ agg, float* __restrict__ stats, int N) {
    __shared__ u32 seg[SEGCAP];
    __shared__ u32 lrows[SEGCAP];
    __shared__ int lcnt[64], lstart[64], lcur[64];
    __shared__ float rs[4][64], rq[4][64];
    int b = blockIdx.x, t = threadIdx.x;
    int lane = t & 63, w = t >> 6;
    int s = bstart[b];
    int cnt = min(bstart[b + 1] - s, SEGCAP);
    if (t < 64) { lcnt[t] = 0; lcur[t] = 0; }
    __syncthreads();
    for (int i = t; i < cnt; i += 256) {
        u32 v = ebuf[s + i];
        seg[i] = v;
        atomicAdd(&lcnt[v & 63u], 1);
    }
    __syncthreads();
    if (w == 0) {  // wave-wide exclusive scan of 64 counts
        int v = lcnt[lane];
        int x = v;
        for (int o = 1; o < 64; o <<= 1) {
            int y = __shfl_up(x, o, 64);
            if (lane >= o) x += y;
        }
        lstart[lane] = x - v;
    }
    __syncthreads();
    for (int i = t; i < cnt; i += 256) {
        u32 v = seg[i];
        int c = (int)(v & 63u);
        int p = lstart[c] + atomicAdd(&lcur[c], 1);
        lrows[p] = v >> 6;
    }
    __syncthreads();
    int node0 = b * 64;
    int g = lane >> 3;       // edge group 0..7
    int sub = lane & 7;      // feature octet: features sub*8 .. sub*8+7
    float ssum[8] = {0.f}, ssq[8] = {0.f};
    for (int i = 0; i < 16; i++) {
        int c = w * 16 + i;
        int node = node0 + c;
        if (node >= N) continue;
        float a[8] = {0.f, 0.f, 0.f, 0.f, 0.f, 0.f, 0.f, 0.f};
        if (g == 0) {  // self-loop message (added by group 0 only)
            uint4 v = ((const uint4*)(m + ((size_t)node << 6)))[sub];
            a[0] = bf2f(v.x & 0xffffu); a[1] = bf2f(v.x >> 16);
            a[2] = bf2f(v.y & 0xffffu); a[3] = bf2f(v.y >> 16);
            a[4] = bf2f(v.z & 0xffffu); a[5] = bf2f(v.z >> 16);
            a[6] = bf2f(v.w & 0xffffu); a[7] = bf2f(v.w >> 16);
        }
        int ls = lstart[c], cntc = lcnt[c];
        #pragma unroll 2
        for (int k = g; k < cntc; k += 8) {
            int r = (int)lrows[ls + k];
            uint4 v = ((const uint4*)(m + ((size_t)r << 6)))[sub];
            a[0] += bf2f(v.x & 0xffffu); a[1] += bf2f(v.x >> 16);
            a[2] += bf2f(v.y & 0xffffu); a[3] += bf2f(v.y >> 16);
            a[4] += bf2f(v.z & 0xffffu); a[5] += bf2f(v.z >> 16);
            a[6] += bf2f(v.w & 0xffffu); a[7] += bf2f(v.w >> 16);
        }
        // reduce across the 8 edge groups (lanes sub, sub+8, ..., sub+56)
        #pragma unroll
        for (int j = 0; j < 8; j++) {
            a[j] += __shfl_xor(a[j], 8, 64);
            a[j] += __shfl_xor(a[j], 16, 64);
            a[j] += __shfl_xor(a[j], 32, 64);
        }
        if (lane < 8) {
            float di = dinv[node];
            float4 lo, hi;
            lo.x = a[0] * di; lo.y = a[1] * di; lo.z = a[2] * di; lo.w = a[3] * di;
            hi.x = a[4] * di; hi.y = a[5] * di; hi.z = a[6] * di; hi.w = a[7] * di;
            *(float4*)(agg + ((size_t)node << 6) + sub * 8)     = lo;
            *(float4*)(agg + ((size_t)node << 6) + sub * 8 + 4) = hi;
            ssum[0] += lo.x; ssum[1] += lo.y; ssum[2] += lo.z; ssum[3] += lo.w;
            ssum[4] += hi.x; ssum[5] += hi.y; ssum[6] += hi.z; ssum[7] += hi.w;
            ssq[0] += lo.x * lo.x; ssq[1] += lo.y * lo.y;
            ssq[2] += lo.z * lo.z; ssq[3] += lo.w * lo.w;
            ssq[4] += hi.x * hi.x; ssq[5] += hi.y * hi.y;
            ssq[6] += hi.z * hi.z; ssq[7] += hi.w * hi.w;
        }
    }
    if (lane < 8) {
        #pragma unroll
        for (int j = 0; j < 8; j++) {
            rs[w][sub * 8 + j] = ssum[j];
            rq[w][sub * 8 + j] = ssq[j];
        }
    }
    __syncthreads();
    if (w == 0) {
        float a = rs[0][lane] + rs[1][lane] + rs[2][lane] + rs[3][lane];
        float q = rq[0][lane] + rq[1][lane] + rq[2][lane] + rq[3][lane];
        atomicAdd(&stats[lane], a);
        atomicAdd(&stats[64 + lane], q);
    }
}

// sorted-batch run-length pooling with BN3+relu applied inline.
__global__ void k_pool(const float* __restrict__ agg3, const float* __restrict__ st3,
                       const float* __restrict__ g3, const float* __restrict__ be3,
                       const int* __restrict__ batch, float* __restrict__ pooled,
                       float* __restrict__ gcnt, int N) {
    int lane = threadIdx.x;  // blockDim = 64
    int start = blockIdx.x * 64;
    if (start >= N) return;
    const float invN = 1.0f / (float)N;
    float mean = st3[lane] * invN;
    float var = st3[64 + lane] * invN - mean * mean;
    float sc = g3[lane] * rsqrtf(var + BN_EPS);
    float bb = be3[lane];
    int end = min(start + 64, N);
    int gcur = batch[start];
    float acc = 0.f; int run = 0;
    for (int n = start; n < end; n++) {
        int g = batch[n];
        if (g != gcur) {
            atomicAdd(&pooled[gcur * HID + lane], acc);
            if (lane == 0) atomicAdd(&gcnt[gcur], (float)run);
            acc = 0.f; run = 0; gcur = g;
        }
        acc += fmaxf((agg3[(size_t)n * HID + lane] - mean) * sc + bb, 0.f);
        run++;
    }
    atomicAdd(&pooled[gcur * HID + lane], acc);
    if (lane == 0) atomicAdd(&gcnt[gcur], (float)run);
}

// out[g] = dot(pooled[g]/max(cnt,1), fcw) + fcb.  wave per graph.
__global__ void k_final(const float* __restrict__ pooled, const float* __restrict__ gcnt,
                        const float* __restrict__ fcw, const float* __restrict__ fcb,
                        float* __restrict__ out) {
    int g = (int)((blockIdx.x * (size_t)blockDim.x + threadIdx.x) >> 6);
    int lane = threadIdx.x & 63;
    if (g >= NG) return;
    float c = fmaxf(gcnt[g], 1.f);
    float v = pooled[g * HID + lane] / c * fcw[lane];
    for (int off = 32; off > 0; off >>= 1) v += __shfl_down(v, off, 64);
    if (lane == 0) out[g] = v + fcb[0];
}

// ---------------- launch ----------------

extern "C" void kernel_launch(void* const* d_in, const int* in_sizes, int n_in,
                              void* d_out, int out_size, void* d_ws, size_t ws_size,
                              hipStream_t stream) {
    const float* x    = (const float*)d_in[0];
    const int*   ei   = (const int*)d_in[1];
    const int*   batch= (const int*)d_in[2];
    const float* w1   = (const float*)d_in[3];
    const float* g1   = (const float*)d_in[5];
    const float* be1  = (const float*)d_in[6];
    const float* w2   = (const float*)d_in[7];
    const float* g2   = (const float*)d_in[9];
    const float* be2  = (const float*)d_in[10];
    const float* w3   = (const float*)d_in[11];
    const float* g3   = (const float*)d_in[13];
    const float* be3  = (const float*)d_in[14];
    const float* fcw  = (const float*)d_in[15];
    const float* fcb  = (const float*)d_in[16];
    float* out = (float*)d_out;

    const int N = NN, E = NE;
    const int* erow = ei;       // edge_index[0] = source
    const int* ecol = ei + E;   // edge_index[1] = target

    char* ws = (char*)d_ws;
    size_t off = 0;
    auto alloc = [&](size_t bytes) -> char* {
        char* p = ws + off;
        off = (off + bytes + 255) & ~(size_t)255;
        return p;
    };
    float* dinv   = (float*)alloc((size_t)N * 4);
    int*   hist   = (int*)alloc((size_t)SCB * NB * 4);   // per-block bucket bases
    int*   bcnt   = (int*)alloc((size_t)NB * 4);
    int*   bstart = (int*)alloc((size_t)(NB + 1) * 4);
    u32*   ebuf   = (u32*)alloc((size_t)E * 4);          // bucketized packed edges
    u16*   bufM   = (u16*)alloc((size_t)N * HID * 2);    // m' (bf16, dinv-scaled)
    float* aggB1  = (float*)alloc((size_t)N * HID * 4);  // agg1, reused as agg3
    float* aggB2  = (float*)alloc((size_t)N * HID * 4);  // agg2
    float* stats  = (float*)alloc(3 * 128 * 4);
    float* pooled = (float*)alloc((size_t)NG * HID * 4);
    float* gcnt   = (float*)alloc((size_t)NG * 4);
    (void)ws_size; (void)in_sizes; (void)n_in; (void)out_size;

    float* aggB3 = aggB1;  // agg1 last read in k_gemm3, before layer-3 agg

    hipMemsetAsync(stats, 0, 3 * 128 * 4, stream);
    hipMemsetAsync(pooled, 0, (size_t)NG * HID * 4, stream);
    hipMemsetAsync(gcnt, 0, (size_t)NG * 4, stream);

    const int nbNode16 = (N + 15) / 16;    // 6250
    const int nbB = (NB + 255) / 256;      // 7

    // graph build: multisplit with private regions
    k_hist<<<SCB, 256, 0, stream>>>(ecol, hist, E);
    k_btot<<<nbB, 256, 0, stream>>>(hist, bcnt);
    k_bscan<<<1, 256, 0, stream>>>(bcnt, bstart, NB, E);
    k_hcol<<<nbB, 256, 0, stream>>>(hist, bstart);
    k_scatter<<<SCB, 256, 0, stream>>>(erow, ecol, hist, ebuf, E);
    k_degb<<<NB, 256, 0, stream>>>(ebuf, bstart, dinv, N);

    // layer 1
    k_gemm<INDIM><<<nbNode16, 256, 0, stream>>>(x, w1, dinv, bufM, N,
                                                nullptr, nullptr, nullptr);
    k_fusedagg<<<NB, 256, 0, stream>>>(bufM, dinv, ebuf, bstart, aggB1, stats, N);

    // layer 2 (gemm stages relu(BN1(agg1)))
    k_gemm<HID><<<nbNode16, 256, 0, stream>>>(aggB1, w2, dinv, bufM, N,
                                              stats, g1, be1);
    k_fusedagg<<<NB, 256, 0, stream>>>(bufM, dinv, ebuf, bstart, aggB2, stats + 128, N);

    // layer 3 (gemm stages h2 = relu(BN2(agg2) + relu(BN1(agg1))))
    k_gemm3<<<nbNode16, 256, 0, stream>>>(aggB1, aggB2, stats, stats + 128,
                                          g1, be1, g2, be2, w3, dinv, bufM, N);
    k_fusedagg<<<NB, 256, 0, stream>>>(bufM, dinv, ebuf, bstart, aggB3, stats + 256, N);

    // pool (BN3+relu inline) + final
    k_pool<<<(N + 63) / 64, 64, 0, stream>>>(aggB3, stats + 256, g3, be3,
                                             batch, pooled, gcnt, N);
    k_final<<<(NG * 64) / 256, 256, 0, stream>>>(pooled, gcnt, fcw, fcb, out);
}